// Round 16
// baseline (98.213 us; speedup 1.0000x reference)
//
#include <hip/hip_runtime.h>
#include <math.h>

// StyleGAN2 2x upsample blur (upfirdn2d, up=2, f=[1,3,3,1], gain=4).
// R15 (74.1us, best): warm kernel (pure-read, input -> L3) + R14 main.
// THIS ROUND (single variable): main-kernel output stores -> NONTEMPORAL.
// Theory: the 268MB store stream sweeps L2/L3 and evicts the warmed input
// before late units read it (R13 steady-hot = 54.5us vs our main ~63us);
// nt stores don't displace cache -> input stays L3-resident all kernel.
// (R10's nt null was in the cold-mixed regime, bundled with a structural
// change — not a valid test of this.)

typedef float vfloat4 __attribute__((ext_vector_type(4)));

// ---------------- K1: warm ----------------
__global__ __launch_bounds__(256) void warm_kernel(
    const float4* __restrict__ x, int n4, float* __restrict__ ws, int nws) {
    int tid = blockIdx.x * 256 + threadIdx.x;
    int stride = gridDim.x * 256;
    float s = 0.f;
    for (int i = tid; i < n4; i += stride) {
        float4 v = x[i];
        s += v.x + v.y + v.z + v.w;
    }
    for (int off = 32; off > 0; off >>= 1) s += __shfl_down(s, off);
    __shared__ float sm[4];
    if ((threadIdx.x & 63) == 0) sm[threadIdx.x >> 6] = s;
    __syncthreads();
    if (threadIdx.x == 0) {
        float t = sm[0] + sm[1] + sm[2] + sm[3];
        if ((int)blockIdx.x < nws) ws[blockIdx.x] = t;  // defeat DCE
    }
}

// ---------------- K2: main (R14 + nt stores) ----------------
template<int S>
__device__ __forceinline__ void hblend(float v0, float v1, float vm1,
                                       float vp0, float vp1, float q[4]) {
    if (S == 0) {
        q[0] = 0.25f*vm1 + 0.75f*v0;
        q[1] = 0.75f*v0  + 0.25f*v1;
        q[2] = 0.25f*v0  + 0.75f*v1;
        q[3] = 0.75f*v1  + 0.25f*vp0;
    } else if (S == 1) {
        q[0] = 0.75f*v0  + 0.25f*v1;
        q[1] = 0.25f*v0  + 0.75f*v1;
        q[2] = 0.75f*v1  + 0.25f*vp0;
        q[3] = 0.25f*v1  + 0.75f*vp0;
    } else if (S == 2) {
        q[0] = 0.25f*v0  + 0.75f*v1;
        q[1] = 0.75f*v1  + 0.25f*vp0;
        q[2] = 0.25f*v1  + 0.75f*vp0;
        q[3] = 0.75f*vp0 + 0.25f*vp1;
    } else {
        q[0] = 0.75f*v1  + 0.25f*vp0;
        q[1] = 0.25f*v1  + 0.75f*vp0;
        q[2] = 0.75f*vp0 + 0.25f*vp1;
        q[3] = 0.25f*vp0 + 0.75f*vp1;
    }
}

template<int S>
__device__ __forceinline__ void store_row(float* __restrict__ rp, int lane,
                                          int Wo, const float q1[4],
                                          const float q2[4],
                                          float v0lane, float v1lane) {
    vfloat4 w1 = {q1[0], q1[1], q1[2], q1[3]};
    __builtin_nontemporal_store(w1, (vfloat4*)(rp + S + 4 * lane));
    int c0 = S + 256 + 4 * lane;
    if (c0 + 3 < Wo) {
        vfloat4 w2 = {q2[0], q2[1], q2[2], q2[3]};
        __builtin_nontemporal_store(w2, (vfloat4*)(rp + c0));
    } else {
        if (c0     < Wo) __builtin_nontemporal_store(q2[0], rp + c0);
        if (c0 + 1 < Wo) __builtin_nontemporal_store(q2[1], rp + c0 + 1);
        if (c0 + 2 < Wo) __builtin_nontemporal_store(q2[2], rp + c0 + 2);
        if (c0 + 3 < Wo) __builtin_nontemporal_store(q2[3], rp + c0 + 3);
    }
    if (S > 0 && lane == 0) {
        __builtin_nontemporal_store(0.75f * v0lane, rp);
        if (S > 1) __builtin_nontemporal_store(0.75f * v0lane + 0.25f * v1lane, rp + 1);
        if (S > 2) __builtin_nontemporal_store(0.25f * v0lane + 0.75f * v1lane, rp + 2);
    }
}

template<int SE>
__device__ __forceinline__ void emit_pair(
    float2 a1, float2 b1, float2 c1, float2 a2, float2 b2, float2 c2,
    float w0, float wp, float* __restrict__ out, size_t be,
    int lane, int orow, int Ho, int Wo) {
    constexpr int SO = (SE + 1) & 3;

    float ve10 = w0*a1.x + 0.75f*b1.x, ve11 = w0*a1.y + 0.75f*b1.y;
    float ve20 = w0*a2.x + 0.75f*b2.x, ve21 = w0*a2.y + 0.75f*b2.y;
    float vo10 = 0.75f*b1.x + wp*c1.x, vo11 = 0.75f*b1.y + wp*c1.y;
    float vo20 = 0.75f*b2.x + wp*c2.x, vo21 = 0.75f*b2.y + wp*c2.y;

    float t;
    float vm1e1 = __shfl_up(ve11, 1);   if (lane == 0)  vm1e1 = 0.f;
    float vp0e1 = __shfl_down(ve10, 1);
    t = __shfl(ve20, 0);                if (lane == 63) vp0e1 = t;
    float vp1e1 = __shfl_down(ve11, 1);
    t = __shfl(ve21, 0);                if (lane == 63) vp1e1 = t;
    float vm1e2 = __shfl_up(ve21, 1);
    t = __shfl(ve11, 63);               if (lane == 0)  vm1e2 = t;
    float vp0e2 = __shfl_down(ve20, 1); if (lane == 63) vp0e2 = 0.f;
    float vp1e2 = __shfl_down(ve21, 1); if (lane == 63) vp1e2 = 0.f;
    float vm1o1 = __shfl_up(vo11, 1);   if (lane == 0)  vm1o1 = 0.f;
    float vp0o1 = __shfl_down(vo10, 1);
    t = __shfl(vo20, 0);                if (lane == 63) vp0o1 = t;
    float vp1o1 = __shfl_down(vo11, 1);
    t = __shfl(vo21, 0);                if (lane == 63) vp1o1 = t;
    float vm1o2 = __shfl_up(vo21, 1);
    t = __shfl(vo11, 63);               if (lane == 0)  vm1o2 = t;
    float vp0o2 = __shfl_down(vo20, 1); if (lane == 63) vp0o2 = 0.f;
    float vp1o2 = __shfl_down(vo21, 1); if (lane == 63) vp1o2 = 0.f;

    float q1[4], q2[4];
    float* re = out + be;
    hblend<SE>(ve10, ve11, vm1e1, vp0e1, vp1e1, q1);
    hblend<SE>(ve20, ve21, vm1e2, vp0e2, vp1e2, q2);
    store_row<SE>(re, lane, Wo, q1, q2, ve10, ve11);

    if (orow + 1 < Ho) {
        float* ro = re + Wo;
        hblend<SO>(vo10, vo11, vm1o1, vp0o1, vp1o1, q1);
        hblend<SO>(vo20, vo21, vm1o2, vp0o2, vp1o2, q2);
        store_row<SO>(ro, lane, Wo, q1, q2, vo10, vo11);
    }
}

__device__ __forceinline__ void ldrow(const float* __restrict__ xp, int row,
                                      int lane, int W, float2& w1, float2& w2) {
    const float2* p = (const float2*)(xp + row * W);
    w1 = p[lane];
    w2 = p[64 + lane];
}

template<int S0>
__device__ __forceinline__ void run_wave(const float* __restrict__ xp,
                                         float* __restrict__ out, size_t obase,
                                         int rbase, int lane,
                                         int H, int W, int Ho, int Wo) {
    float2 A1, A2, B1, B2, C1, C2, D1, D2, E1, E2, F1, F2;
    int r0 = rbase;
    ldrow(xp, 2*r0 - 1 > 0 ? 2*r0 - 1 : 0, lane, W, A1, A2);
    ldrow(xp, 2*r0,                        lane, W, B1, B2);
    ldrow(xp, 2*r0 + 1,                    lane, W, C1, C2);
    ldrow(xp, 2*r0 + 2 < H ? 2*r0 + 2 : H - 1, lane, W, D1, D2);

#pragma unroll
    for (int k = 0; k < 4; ++k) {
        int rr = rbase + k;
        if (k < 3) {
            ldrow(xp, 2*rr + 3, lane, W, E1, E2);
            ldrow(xp, 2*rr + 4 < H ? 2*rr + 4 : H - 1, lane, W, F1, F2);
        }
        float w_top = (rr > 0) ? 0.25f : 0.0f;
        float w_bot = (2*rr + 1 < H - 1) ? 0.25f : 0.0f;
        size_t be0 = obase + (size_t)(4 * rr) * Wo;
        size_t be1 = be0 + 2 * (size_t)Wo;
        emit_pair<S0>(A1, B1, C1, A2, B2, C2, w_top, 0.25f,
                      out, be0, lane, 4 * rr, Ho, Wo);
        emit_pair<(S0 + 2) & 3>(B1, C1, D1, B2, C2, D2, 0.25f, w_bot,
                                out, be1, lane, 4 * rr + 2, Ho, Wo);
        A1 = C1; A2 = C2; B1 = D1; B2 = D2;
        C1 = E1; C2 = E2; D1 = F1; D2 = F2;
    }
}

__global__ __launch_bounds__(256) void blur_up2_kernel(
    const float* __restrict__ x, float* __restrict__ out,
    int H, int W, int Ho, int Wo) {
    int lane = threadIdx.x;
    int w = blockIdx.x * 4 + threadIdx.y;
    int ch = w >> 5;
    int rbase = (w & 31) * 4;

    const float* xp = x + (size_t)ch * H * W;
    size_t obase = (size_t)ch * Ho * Wo;
    size_t be0 = obase + (size_t)(4 * rbase) * Wo;
    int S0 = (int)((4 - (be0 & 3)) & 3);
    switch (S0) {
        case 0:  run_wave<0>(xp, out, obase, rbase, lane, H, W, Ho, Wo); break;
        case 1:  run_wave<1>(xp, out, obase, rbase, lane, H, W, Ho, Wo); break;
        case 2:  run_wave<2>(xp, out, obase, rbase, lane, H, W, Ho, Wo); break;
        default: run_wave<3>(xp, out, obase, rbase, lane, H, W, Ho, Wo); break;
    }
}

extern "C" void kernel_launch(void* const* d_in, const int* in_sizes, int n_in,
                              void* d_out, int out_size, void* d_ws, size_t ws_size,
                              hipStream_t stream) {
    const float* x = (const float*)d_in[0];
    float* out = (float*)d_out;

    const int H = 256, W = 256;
    int NC = in_sizes[0] / (H * W);  // 256

    int hw_out = out_size / NC;
    int Wo = (int)(sqrt((double)hw_out) + 0.5);
    int Ho = hw_out / Wo;

    int n4 = in_sizes[0] / 4;
    int nws = (int)(ws_size / sizeof(float));
    warm_kernel<<<2048, 256, 0, stream>>>((const float4*)x, n4,
                                          (float*)d_ws, nws);

    dim3 block(64, 4);
    dim3 grid(NC * 8);
    blur_up2_kernel<<<grid, block, 0, stream>>>(x, out, H, W, Ho, Wo);
}

// Round 17
// 75.110 us; speedup vs baseline: 1.3076x; 1.3076x over previous
//
#include <hip/hip_runtime.h>
#include <math.h>

// StyleGAN2 2x upsample blur (upfirdn2d, up=2, f=[1,3,3,1], gain=4).
// R15 (74.1us best): warm (input->L3) + R14 main, plain stores.
// R16 falsified nt stores (-24us). THIS ROUND (single variable): halve the
// number of concurrent write streams. 4096 waves (16/CU), each owning 8
// row-pairs = 64KB contiguous write (vs 8192 x 32KB). Evidence: fill hits
// 7.1 TB/s with ~900 streams @11% occupancy; our main ~4.5 TB/s with ~5900
// streams @71% occupancy -> HBM page thrash scales with stream count.

typedef float vfloat4 __attribute__((ext_vector_type(4)));

// ---------------- K1: warm ----------------
__global__ __launch_bounds__(256) void warm_kernel(
    const float4* __restrict__ x, int n4, float* __restrict__ ws, int nws) {
    int tid = blockIdx.x * 256 + threadIdx.x;
    int stride = gridDim.x * 256;
    float s = 0.f;
    for (int i = tid; i < n4; i += stride) {
        float4 v = x[i];
        s += v.x + v.y + v.z + v.w;
    }
    for (int off = 32; off > 0; off >>= 1) s += __shfl_down(s, off);
    __shared__ float sm[4];
    if ((threadIdx.x & 63) == 0) sm[threadIdx.x >> 6] = s;
    __syncthreads();
    if (threadIdx.x == 0) {
        float t = sm[0] + sm[1] + sm[2] + sm[3];
        if ((int)blockIdx.x < nws) ws[blockIdx.x] = t;  // defeat DCE
    }
}

// ---------------- K2: main ----------------
template<int S>
__device__ __forceinline__ void hblend(float v0, float v1, float vm1,
                                       float vp0, float vp1, float q[4]) {
    if (S == 0) {
        q[0] = 0.25f*vm1 + 0.75f*v0;
        q[1] = 0.75f*v0  + 0.25f*v1;
        q[2] = 0.25f*v0  + 0.75f*v1;
        q[3] = 0.75f*v1  + 0.25f*vp0;
    } else if (S == 1) {
        q[0] = 0.75f*v0  + 0.25f*v1;
        q[1] = 0.25f*v0  + 0.75f*v1;
        q[2] = 0.75f*v1  + 0.25f*vp0;
        q[3] = 0.25f*v1  + 0.75f*vp0;
    } else if (S == 2) {
        q[0] = 0.25f*v0  + 0.75f*v1;
        q[1] = 0.75f*v1  + 0.25f*vp0;
        q[2] = 0.25f*v1  + 0.75f*vp0;
        q[3] = 0.75f*vp0 + 0.25f*vp1;
    } else {
        q[0] = 0.75f*v1  + 0.25f*vp0;
        q[1] = 0.25f*v1  + 0.75f*vp0;
        q[2] = 0.75f*vp0 + 0.25f*vp1;
        q[3] = 0.25f*vp0 + 0.75f*vp1;
    }
}

template<int S>
__device__ __forceinline__ void store_row(float* __restrict__ rp, int lane,
                                          int Wo, const float q1[4],
                                          const float q2[4],
                                          float v0lane, float v1lane) {
    *(float4*)(rp + S + 4 * lane) = make_float4(q1[0], q1[1], q1[2], q1[3]);
    int c0 = S + 256 + 4 * lane;
    if (c0 + 3 < Wo) {
        *(float4*)(rp + c0) = make_float4(q2[0], q2[1], q2[2], q2[3]);
    } else {
        if (c0     < Wo) rp[c0]     = q2[0];
        if (c0 + 1 < Wo) rp[c0 + 1] = q2[1];
        if (c0 + 2 < Wo) rp[c0 + 2] = q2[2];
        if (c0 + 3 < Wo) rp[c0 + 3] = q2[3];
    }
    if (S > 0 && lane == 0) {
        rp[0] = 0.75f * v0lane;
        if (S > 1) rp[1] = 0.75f * v0lane + 0.25f * v1lane;
        if (S > 2) rp[2] = 0.25f * v0lane + 0.75f * v1lane;
    }
}

template<int SE>
__device__ __forceinline__ void emit_pair(
    float2 a1, float2 b1, float2 c1, float2 a2, float2 b2, float2 c2,
    float w0, float wp, float* __restrict__ out, size_t be,
    int lane, int orow, int Ho, int Wo) {
    constexpr int SO = (SE + 1) & 3;

    float ve10 = w0*a1.x + 0.75f*b1.x, ve11 = w0*a1.y + 0.75f*b1.y;
    float ve20 = w0*a2.x + 0.75f*b2.x, ve21 = w0*a2.y + 0.75f*b2.y;
    float vo10 = 0.75f*b1.x + wp*c1.x, vo11 = 0.75f*b1.y + wp*c1.y;
    float vo20 = 0.75f*b2.x + wp*c2.x, vo21 = 0.75f*b2.y + wp*c2.y;

    float t;
    float vm1e1 = __shfl_up(ve11, 1);   if (lane == 0)  vm1e1 = 0.f;
    float vp0e1 = __shfl_down(ve10, 1);
    t = __shfl(ve20, 0);                if (lane == 63) vp0e1 = t;
    float vp1e1 = __shfl_down(ve11, 1);
    t = __shfl(ve21, 0);                if (lane == 63) vp1e1 = t;
    float vm1e2 = __shfl_up(ve21, 1);
    t = __shfl(ve11, 63);               if (lane == 0)  vm1e2 = t;
    float vp0e2 = __shfl_down(ve20, 1); if (lane == 63) vp0e2 = 0.f;
    float vp1e2 = __shfl_down(ve21, 1); if (lane == 63) vp1e2 = 0.f;
    float vm1o1 = __shfl_up(vo11, 1);   if (lane == 0)  vm1o1 = 0.f;
    float vp0o1 = __shfl_down(vo10, 1);
    t = __shfl(vo20, 0);                if (lane == 63) vp0o1 = t;
    float vp1o1 = __shfl_down(vo11, 1);
    t = __shfl(vo21, 0);                if (lane == 63) vp1o1 = t;
    float vm1o2 = __shfl_up(vo21, 1);
    t = __shfl(vo11, 63);               if (lane == 0)  vm1o2 = t;
    float vp0o2 = __shfl_down(vo20, 1); if (lane == 63) vp0o2 = 0.f;
    float vp1o2 = __shfl_down(vo21, 1); if (lane == 63) vp1o2 = 0.f;

    float q1[4], q2[4];
    float* re = out + be;
    hblend<SE>(ve10, ve11, vm1e1, vp0e1, vp1e1, q1);
    hblend<SE>(ve20, ve21, vm1e2, vp0e2, vp1e2, q2);
    store_row<SE>(re, lane, Wo, q1, q2, ve10, ve11);

    if (orow + 1 < Ho) {
        float* ro = re + Wo;
        hblend<SO>(vo10, vo11, vm1o1, vp0o1, vp1o1, q1);
        hblend<SO>(vo20, vo21, vm1o2, vp0o2, vp1o2, q2);
        store_row<SO>(ro, lane, Wo, q1, q2, vo10, vo11);
    }
}

__device__ __forceinline__ void ldrow(const float* __restrict__ xp, int row,
                                      int lane, int W, float2& w1, float2& w2) {
    const float2* p = (const float2*)(xp + row * W);
    w1 = p[lane];
    w2 = p[64 + lane];
}

template<int S0>
__device__ __forceinline__ void run_wave(const float* __restrict__ xp,
                                         float* __restrict__ out, size_t obase,
                                         int rbase, int lane,
                                         int H, int W, int Ho, int Wo) {
    // rolling window rows A=2r-1, B=2r, C=2r+1, D=2r+2 (two col-windows)
    float2 A1, A2, B1, B2, C1, C2, D1, D2, E1, E2, F1, F2;
    int r0 = rbase;
    ldrow(xp, 2*r0 - 1 > 0 ? 2*r0 - 1 : 0, lane, W, A1, A2);
    ldrow(xp, 2*r0,                        lane, W, B1, B2);
    ldrow(xp, 2*r0 + 1,                    lane, W, C1, C2);
    ldrow(xp, 2*r0 + 2 < H ? 2*r0 + 2 : H - 1, lane, W, D1, D2);

#pragma unroll
    for (int k = 0; k < 8; ++k) {              // 8 row-pairs per wave
        int rr = rbase + k;
        if (k < 7) {   // prefetch next unit's two rows BEFORE stores
            ldrow(xp, 2*rr + 3, lane, W, E1, E2);
            ldrow(xp, 2*rr + 4 < H ? 2*rr + 4 : H - 1, lane, W, F1, F2);
        }
        float w_top = (rr > 0) ? 0.25f : 0.0f;
        float w_bot = (2*rr + 1 < H - 1) ? 0.25f : 0.0f;
        size_t be0 = obase + (size_t)(4 * rr) * Wo;
        size_t be1 = be0 + 2 * (size_t)Wo;
        emit_pair<S0>(A1, B1, C1, A2, B2, C2, w_top, 0.25f,
                      out, be0, lane, 4 * rr, Ho, Wo);
        emit_pair<(S0 + 2) & 3>(B1, C1, D1, B2, C2, D2, 0.25f, w_bot,
                                out, be1, lane, 4 * rr + 2, Ho, Wo);
        A1 = C1; A2 = C2; B1 = D1; B2 = D2;
        C1 = E1; C2 = E2; D1 = F1; D2 = F2;
    }
}

__global__ __launch_bounds__(128) void blur_up2_kernel(
    const float* __restrict__ x, float* __restrict__ out,
    int H, int W, int Ho, int Wo) {
    int lane = threadIdx.x;                    // 0..63
    int w = blockIdx.x * 2 + threadIdx.y;      // global wave id (2 waves/blk)
    int ch = w >> 4;                           // channel (16 waves/channel)
    int rbase = (w & 15) * 8;                  // first row-pair (8 per wave)

    const float* xp = x + (size_t)ch * H * W;
    size_t obase = (size_t)ch * Ho * Wo;
    size_t be0 = obase + (size_t)(4 * rbase) * Wo;
    int S0 = (int)((4 - (be0 & 3)) & 3);       // constant across wave's units
    switch (S0) {
        case 0:  run_wave<0>(xp, out, obase, rbase, lane, H, W, Ho, Wo); break;
        case 1:  run_wave<1>(xp, out, obase, rbase, lane, H, W, Ho, Wo); break;
        case 2:  run_wave<2>(xp, out, obase, rbase, lane, H, W, Ho, Wo); break;
        default: run_wave<3>(xp, out, obase, rbase, lane, H, W, Ho, Wo); break;
    }
}

extern "C" void kernel_launch(void* const* d_in, const int* in_sizes, int n_in,
                              void* d_out, int out_size, void* d_ws, size_t ws_size,
                              hipStream_t stream) {
    const float* x = (const float*)d_in[0];
    float* out = (float*)d_out;

    const int H = 256, W = 256;
    int NC = in_sizes[0] / (H * W);  // 256

    int hw_out = out_size / NC;
    int Wo = (int)(sqrt((double)hw_out) + 0.5);
    int Ho = hw_out / Wo;

    // K1: pure-read warm sweep of the input into L3
    int n4 = in_sizes[0] / 4;
    int nws = (int)(ws_size / sizeof(float));
    warm_kernel<<<2048, 256, 0, stream>>>((const float4*)x, n4,
                                          (float*)d_ws, nws);

    // K2: main blur — 4096 waves, 16 waves/channel, 8 row-pairs each
    dim3 block(64, 2);
    dim3 grid(NC * 8);
    blur_up2_kernel<<<grid, block, 0, stream>>>(x, out, H, W, Ho, Wo);
}

// Round 18
// 73.343 us; speedup vs baseline: 1.3391x; 1.0241x over previous
//
#include <hip/hip_runtime.h>
#include <math.h>

// StyleGAN2 2x upsample blur (upfirdn2d, up=2, f=[1,3,3,1], gain=4).
// FINAL (R15 restoration, 74.1us): warm kernel (pure-read sweep -> input
// L3-resident) + R14 main (persistent waves, rolling register row-window,
// line-dense S-shifted float4 stores).
//
// Ledger (17 rounds):
//   WIN  line-dense stores (16B/lane stride, no partial-line RFO)   R7->R8 +12us
//   WIN  read/write stream segregation via warm prologue            R14->R15 +6us
//   NULL per-wave latency structure (1 vs 4 stalls/wave)            R13->R14
//   NULL DRAM page/stream structure (runs/band/count)               R7/R11/R17
//   NEG  nontemporal stores (gfx950: forces early evict)            R10/R16
// Fabric arithmetic: main-hot moves 268MB HBM-W + ~60MB L3-R = 328MB in
// ~55us = 6.0 TB/s ~= 95% of the 6.3 TB/s copy ceiling. Floor ~53us + warm
// ~11us + ramp ~8us == measured 74us. Within a few % of machine limit.

typedef float vfloat4 __attribute__((ext_vector_type(4)));

// ---------------- K1: warm ----------------
__global__ __launch_bounds__(256) void warm_kernel(
    const float4* __restrict__ x, int n4, float* __restrict__ ws, int nws) {
    int tid = blockIdx.x * 256 + threadIdx.x;
    int stride = gridDim.x * 256;
    float s = 0.f;
    for (int i = tid; i < n4; i += stride) {
        float4 v = x[i];
        s += v.x + v.y + v.z + v.w;
    }
    for (int off = 32; off > 0; off >>= 1) s += __shfl_down(s, off);
    __shared__ float sm[4];
    if ((threadIdx.x & 63) == 0) sm[threadIdx.x >> 6] = s;
    __syncthreads();
    if (threadIdx.x == 0) {
        float t = sm[0] + sm[1] + sm[2] + sm[3];
        if ((int)blockIdx.x < nws) ws[blockIdx.x] = t;  // defeat DCE
    }
}

// ---------------- K2: main ----------------
template<int S>
__device__ __forceinline__ void hblend(float v0, float v1, float vm1,
                                       float vp0, float vp1, float q[4]) {
    if (S == 0) {
        q[0] = 0.25f*vm1 + 0.75f*v0;
        q[1] = 0.75f*v0  + 0.25f*v1;
        q[2] = 0.25f*v0  + 0.75f*v1;
        q[3] = 0.75f*v1  + 0.25f*vp0;
    } else if (S == 1) {
        q[0] = 0.75f*v0  + 0.25f*v1;
        q[1] = 0.25f*v0  + 0.75f*v1;
        q[2] = 0.75f*v1  + 0.25f*vp0;
        q[3] = 0.25f*v1  + 0.75f*vp0;
    } else if (S == 2) {
        q[0] = 0.25f*v0  + 0.75f*v1;
        q[1] = 0.75f*v1  + 0.25f*vp0;
        q[2] = 0.25f*v1  + 0.75f*vp0;
        q[3] = 0.75f*vp0 + 0.25f*vp1;
    } else {
        q[0] = 0.75f*v1  + 0.25f*vp0;
        q[1] = 0.25f*v1  + 0.75f*vp0;
        q[2] = 0.75f*vp0 + 0.25f*vp1;
        q[3] = 0.25f*vp0 + 0.75f*vp1;
    }
}

template<int S>
__device__ __forceinline__ void store_row(float* __restrict__ rp, int lane,
                                          int Wo, const float q1[4],
                                          const float q2[4],
                                          float v0lane, float v1lane) {
    *(float4*)(rp + S + 4 * lane) = make_float4(q1[0], q1[1], q1[2], q1[3]);
    int c0 = S + 256 + 4 * lane;
    if (c0 + 3 < Wo) {
        *(float4*)(rp + c0) = make_float4(q2[0], q2[1], q2[2], q2[3]);
    } else {
        if (c0     < Wo) rp[c0]     = q2[0];
        if (c0 + 1 < Wo) rp[c0 + 1] = q2[1];
        if (c0 + 2 < Wo) rp[c0 + 2] = q2[2];
        if (c0 + 3 < Wo) rp[c0 + 3] = q2[3];
    }
    if (S > 0 && lane == 0) {
        rp[0] = 0.75f * v0lane;
        if (S > 1) rp[1] = 0.75f * v0lane + 0.25f * v1lane;
        if (S > 2) rp[2] = 0.25f * v0lane + 0.75f * v1lane;
    }
}

template<int SE>
__device__ __forceinline__ void emit_pair(
    float2 a1, float2 b1, float2 c1, float2 a2, float2 b2, float2 c2,
    float w0, float wp, float* __restrict__ out, size_t be,
    int lane, int orow, int Ho, int Wo) {
    constexpr int SO = (SE + 1) & 3;

    float ve10 = w0*a1.x + 0.75f*b1.x, ve11 = w0*a1.y + 0.75f*b1.y;
    float ve20 = w0*a2.x + 0.75f*b2.x, ve21 = w0*a2.y + 0.75f*b2.y;
    float vo10 = 0.75f*b1.x + wp*c1.x, vo11 = 0.75f*b1.y + wp*c1.y;
    float vo20 = 0.75f*b2.x + wp*c2.x, vo21 = 0.75f*b2.y + wp*c2.y;

    float t;
    float vm1e1 = __shfl_up(ve11, 1);   if (lane == 0)  vm1e1 = 0.f;
    float vp0e1 = __shfl_down(ve10, 1);
    t = __shfl(ve20, 0);                if (lane == 63) vp0e1 = t;
    float vp1e1 = __shfl_down(ve11, 1);
    t = __shfl(ve21, 0);                if (lane == 63) vp1e1 = t;
    float vm1e2 = __shfl_up(ve21, 1);
    t = __shfl(ve11, 63);               if (lane == 0)  vm1e2 = t;
    float vp0e2 = __shfl_down(ve20, 1); if (lane == 63) vp0e2 = 0.f;
    float vp1e2 = __shfl_down(ve21, 1); if (lane == 63) vp1e2 = 0.f;
    float vm1o1 = __shfl_up(vo11, 1);   if (lane == 0)  vm1o1 = 0.f;
    float vp0o1 = __shfl_down(vo10, 1);
    t = __shfl(vo20, 0);                if (lane == 63) vp0o1 = t;
    float vp1o1 = __shfl_down(vo11, 1);
    t = __shfl(vo21, 0);                if (lane == 63) vp1o1 = t;
    float vm1o2 = __shfl_up(vo21, 1);
    t = __shfl(vo11, 63);               if (lane == 0)  vm1o2 = t;
    float vp0o2 = __shfl_down(vo20, 1); if (lane == 63) vp0o2 = 0.f;
    float vp1o2 = __shfl_down(vo21, 1); if (lane == 63) vp1o2 = 0.f;

    float q1[4], q2[4];
    float* re = out + be;
    hblend<SE>(ve10, ve11, vm1e1, vp0e1, vp1e1, q1);
    hblend<SE>(ve20, ve21, vm1e2, vp0e2, vp1e2, q2);
    store_row<SE>(re, lane, Wo, q1, q2, ve10, ve11);

    if (orow + 1 < Ho) {
        float* ro = re + Wo;
        hblend<SO>(vo10, vo11, vm1o1, vp0o1, vp1o1, q1);
        hblend<SO>(vo20, vo21, vm1o2, vp0o2, vp1o2, q2);
        store_row<SO>(ro, lane, Wo, q1, q2, vo10, vo11);
    }
}

__device__ __forceinline__ void ldrow(const float* __restrict__ xp, int row,
                                      int lane, int W, float2& w1, float2& w2) {
    const float2* p = (const float2*)(xp + row * W);
    w1 = p[lane];
    w2 = p[64 + lane];
}

template<int S0>
__device__ __forceinline__ void run_wave(const float* __restrict__ xp,
                                         float* __restrict__ out, size_t obase,
                                         int rbase, int lane,
                                         int H, int W, int Ho, int Wo) {
    float2 A1, A2, B1, B2, C1, C2, D1, D2, E1, E2, F1, F2;
    int r0 = rbase;
    ldrow(xp, 2*r0 - 1 > 0 ? 2*r0 - 1 : 0, lane, W, A1, A2);
    ldrow(xp, 2*r0,                        lane, W, B1, B2);
    ldrow(xp, 2*r0 + 1,                    lane, W, C1, C2);
    ldrow(xp, 2*r0 + 2 < H ? 2*r0 + 2 : H - 1, lane, W, D1, D2);

#pragma unroll
    for (int k = 0; k < 4; ++k) {
        int rr = rbase + k;
        if (k < 3) {
            ldrow(xp, 2*rr + 3, lane, W, E1, E2);
            ldrow(xp, 2*rr + 4 < H ? 2*rr + 4 : H - 1, lane, W, F1, F2);
        }
        float w_top = (rr > 0) ? 0.25f : 0.0f;
        float w_bot = (2*rr + 1 < H - 1) ? 0.25f : 0.0f;
        size_t be0 = obase + (size_t)(4 * rr) * Wo;
        size_t be1 = be0 + 2 * (size_t)Wo;
        emit_pair<S0>(A1, B1, C1, A2, B2, C2, w_top, 0.25f,
                      out, be0, lane, 4 * rr, Ho, Wo);
        emit_pair<(S0 + 2) & 3>(B1, C1, D1, B2, C2, D2, 0.25f, w_bot,
                                out, be1, lane, 4 * rr + 2, Ho, Wo);
        A1 = C1; A2 = C2; B1 = D1; B2 = D2;
        C1 = E1; C2 = E2; D1 = F1; D2 = F2;
    }
}

__global__ __launch_bounds__(256) void blur_up2_kernel(
    const float* __restrict__ x, float* __restrict__ out,
    int H, int W, int Ho, int Wo) {
    int lane = threadIdx.x;
    int w = blockIdx.x * 4 + threadIdx.y;
    int ch = w >> 5;
    int rbase = (w & 31) * 4;

    const float* xp = x + (size_t)ch * H * W;
    size_t obase = (size_t)ch * Ho * Wo;
    size_t be0 = obase + (size_t)(4 * rbase) * Wo;
    int S0 = (int)((4 - (be0 & 3)) & 3);
    switch (S0) {
        case 0:  run_wave<0>(xp, out, obase, rbase, lane, H, W, Ho, Wo); break;
        case 1:  run_wave<1>(xp, out, obase, rbase, lane, H, W, Ho, Wo); break;
        case 2:  run_wave<2>(xp, out, obase, rbase, lane, H, W, Ho, Wo); break;
        default: run_wave<3>(xp, out, obase, rbase, lane, H, W, Ho, Wo); break;
    }
}

extern "C" void kernel_launch(void* const* d_in, const int* in_sizes, int n_in,
                              void* d_out, int out_size, void* d_ws, size_t ws_size,
                              hipStream_t stream) {
    const float* x = (const float*)d_in[0];
    float* out = (float*)d_out;

    const int H = 256, W = 256;
    int NC = in_sizes[0] / (H * W);  // 256

    int hw_out = out_size / NC;
    int Wo = (int)(sqrt((double)hw_out) + 0.5);
    int Ho = hw_out / Wo;

    int n4 = in_sizes[0] / 4;
    int nws = (int)(ws_size / sizeof(float));
    warm_kernel<<<2048, 256, 0, stream>>>((const float4*)x, n4,
                                          (float*)d_ws, nws);

    dim3 block(64, 4);
    dim3 grid(NC * 8);
    blur_up2_kernel<<<grid, block, 0, stream>>>(x, out, H, W, Ho, Wo);
}